// Round 1
// baseline (10043.281 us; speedup 1.0000x reference)
//
#include <hip/hip_runtime.h>
#include <cstddef>

// Problem constants (from reference): NH=4, KD=16, AR=4, RES=40, DIM=256,
// HD=64, D=64, N=1600, B=16.
namespace {
constexpr int kNH  = 4;
constexpr int kKD  = 16;
constexpr int kHD  = 64;
constexpr int kD   = 64;
constexpr int kRES = 40;
constexpr int kN   = 1600;   // 40*40
constexpr int kB   = 16;
constexpr int kDIM = 256;
constexpr float kEPS   = 1e-5f;
constexpr float kSCALE = 0.25f;  // KD^-0.5
}  // namespace

// ---------------------------------------------------------------------------
// Kernel 1: depthwise 5x5 conv (SAME) + BN + cascade add (prev head output).
// One block per (b, c) image; 256 threads stride over the 1600 pixels.
// ---------------------------------------------------------------------------
__global__ __launch_bounds__(256) void dwconv_bn_kernel(
    const float* __restrict__ x,
    const float* __restrict__ dw_w,
    const float* __restrict__ dw_g,
    const float* __restrict__ dw_b,
    const float* __restrict__ dw_m,
    const float* __restrict__ dw_v,
    const float* __restrict__ ohead,   // concatenated head outputs (B,256,N)
    float* __restrict__ xi,            // (B,64,N)
    int head, int has_prev) {
  const int bc = blockIdx.x;           // b*64 + c
  const int b = bc >> 6;
  const int c = bc & 63;
  const int gc = head * kHD + c;

  const float* xin = x + ((size_t)b * kDIM + gc) * kN;
  const float* wc = dw_w + (size_t)gc * 25;
  float wreg[25];
#pragma unroll
  for (int t = 0; t < 25; ++t) wreg[t] = wc[t];

  const float sc = dw_g[gc] * rsqrtf(dw_v[gc] + kEPS);
  const float sh = dw_b[gc] - dw_m[gc] * sc;

  const float* prev =
      ohead + ((size_t)b * kDIM + (head - 1) * kD + c) * kN;  // valid if has_prev
  float* xo = xi + ((size_t)b * kHD + c) * kN;

  for (int p = threadIdx.x; p < kN; p += blockDim.x) {
    const int h = p / kRES;
    const int w = p - h * kRES;
    float acc = 0.f;
#pragma unroll
    for (int dh = 0; dh < 5; ++dh) {
      const int hh = h + dh - 2;
      if (hh < 0 || hh >= kRES) continue;
#pragma unroll
      for (int dwi = 0; dwi < 5; ++dwi) {
        const int ww = w + dwi - 2;
        if (ww < 0 || ww >= kRES) continue;
        acc += xin[hh * kRES + ww] * wreg[dh * 5 + dwi];
      }
    }
    float val = acc * sc + sh;
    if (has_prev) val += prev[p];
    xo[p] = val;
  }
}

// ---------------------------------------------------------------------------
// Kernel 2: fused Q/K/V 1x1 conv + BN. 96 output channels: [0,16) q,
// [16,32) k, [32,96) v. One thread per output element; wave-uniform branch
// (N=1600 is a multiple of 64).
// ---------------------------------------------------------------------------
__global__ __launch_bounds__(256) void qkv_kernel(
    const float* __restrict__ xi,
    const float* __restrict__ q_w, const float* __restrict__ q_g,
    const float* __restrict__ q_b, const float* __restrict__ q_m,
    const float* __restrict__ q_v,
    const float* __restrict__ k_w, const float* __restrict__ k_g,
    const float* __restrict__ k_b, const float* __restrict__ k_m,
    const float* __restrict__ k_v,
    const float* __restrict__ v_w, const float* __restrict__ v_g,
    const float* __restrict__ v_b, const float* __restrict__ v_m,
    const float* __restrict__ v_v,
    float* __restrict__ q, float* __restrict__ k, float* __restrict__ v,
    int head) {
  const int idx = blockIdx.x * blockDim.x + threadIdx.x;
  const int n = idx % kN;
  const int t = idx / kN;
  const int ch = t % 96;
  const int b = t / 96;
  if (b >= kB) return;

  const float* xin = xi + (size_t)b * kHD * kN + n;
  const float* wrow;
  float sc, sh;
  float* outp;
  if (ch < kKD) {
    const int r = head * kKD + ch;
    wrow = q_w + (size_t)r * kHD;
    sc = q_g[r] * rsqrtf(q_v[r] + kEPS);
    sh = q_b[r] - q_m[r] * sc;
    outp = q + ((size_t)b * kKD + ch) * kN + n;
  } else if (ch < 2 * kKD) {
    const int r = head * kKD + (ch - kKD);
    wrow = k_w + (size_t)r * kHD;
    sc = k_g[r] * rsqrtf(k_v[r] + kEPS);
    sh = k_b[r] - k_m[r] * sc;
    outp = k + ((size_t)b * kKD + (ch - kKD)) * kN + n;
  } else {
    const int d = ch - 2 * kKD;
    const int r = head * kD + d;
    wrow = v_w + (size_t)r * kHD;
    sc = v_g[r] * rsqrtf(v_v[r] + kEPS);
    sh = v_b[r] - v_m[r] * sc;
    outp = v + ((size_t)b * kD + d) * kN + n;
  }
  float acc = 0.f;
#pragma unroll 8
  for (int c = 0; c < kHD; ++c) acc += wrow[c] * xin[(size_t)c * kN];
  *outp = acc * sc + sh;
}

// ---------------------------------------------------------------------------
// Kernel 3: attention for one query row per block. Scores (1600) staged in
// LDS; block-wide softmax; PV with 4 threads per output dim d.
// ---------------------------------------------------------------------------
__global__ __launch_bounds__(256) void attn_kernel(
    const float* __restrict__ q, const float* __restrict__ k,
    const float* __restrict__ v, const float* __restrict__ attn_bias,
    float* __restrict__ ohead, int head) {
  __shared__ float s[kN];
  __shared__ float red[8];
  const int b = blockIdx.x / kN;
  const int n = blockIdx.x % kN;
  const int tid = threadIdx.x;
  const float* bias = attn_bias + (size_t)head * kN;

  float qreg[kKD];
  const float* qp = q + (size_t)b * kKD * kN + n;
#pragma unroll
  for (int kk = 0; kk < kKD; ++kk) qreg[kk] = qp[kk * kN];

  // Phase 1: scores -> LDS, track local max.
  const float* kp = k + (size_t)b * kKD * kN;
  float lmax = -1e30f;
  for (int m = tid; m < kN; m += 256) {
    float acc = 0.f;
#pragma unroll
    for (int kk = 0; kk < kKD; ++kk) acc += qreg[kk] * kp[kk * kN + m];
    acc = acc * kSCALE + bias[m];
    s[m] = acc;
    lmax = fmaxf(lmax, acc);
  }
#pragma unroll
  for (int off = 32; off > 0; off >>= 1)
    lmax = fmaxf(lmax, __shfl_xor(lmax, off, 64));
  __syncthreads();
  if ((tid & 63) == 0) red[tid >> 6] = lmax;
  __syncthreads();
  const float gmax = fmaxf(fmaxf(red[0], red[1]), fmaxf(red[2], red[3]));

  // Phase 2: exp + sum.
  float lsum = 0.f;
  for (int m = tid; m < kN; m += 256) {
    const float p = __expf(s[m] - gmax);
    s[m] = p;
    lsum += p;
  }
#pragma unroll
  for (int off = 32; off > 0; off >>= 1) lsum += __shfl_xor(lsum, off, 64);
  __syncthreads();
  if ((tid & 63) == 0) red[4 + (tid >> 6)] = lsum;
  __syncthreads();
  const float inv = 1.f / (red[4] + red[5] + red[6] + red[7]);

  // Phase 3: out[d] = inv * sum_m p[m] * v[b,d,m]; 4 threads per d.
  const int d = tid >> 2;
  const int j = tid & 3;
  const float* vp = v + ((size_t)b * kD + d) * kN;
  float acc = 0.f;
  for (int m = j; m < kN; m += 4) acc += s[m] * vp[m];
  acc += __shfl_xor(acc, 1, 64);
  acc += __shfl_xor(acc, 2, 64);
  if (j == 0) ohead[((size_t)b * kDIM + head * kD + d) * kN + n] = acc * inv;
}

// ---------------------------------------------------------------------------
// Kernel 4: projection 1x1 conv (256->256) + BN + ReLU.
// ---------------------------------------------------------------------------
__global__ __launch_bounds__(256) void proj_kernel(
    const float* __restrict__ ohead, const float* __restrict__ pw,
    const float* __restrict__ pg, const float* __restrict__ pb,
    const float* __restrict__ pm, const float* __restrict__ pv,
    float* __restrict__ out) {
  const int idx = blockIdx.x * blockDim.x + threadIdx.x;
  const int n = idx % kN;
  const int t = idx / kN;
  const int o = t % kDIM;
  const int b = t / kDIM;
  if (b >= kB) return;
  const float* wrow = pw + (size_t)o * kDIM;
  const float* xin = ohead + (size_t)b * kDIM * kN + n;
  float acc = 0.f;
#pragma unroll 8
  for (int c = 0; c < kDIM; ++c) acc += wrow[c] * xin[(size_t)c * kN];
  const float sc = pg[o] * rsqrtf(pv[o] + kEPS);
  const float val = (acc - pm[o]) * sc + pb[o];
  out[idx] = fmaxf(val, 0.f);
}

// ---------------------------------------------------------------------------
extern "C" void kernel_launch(void* const* d_in, const int* in_sizes, int n_in,
                              void* d_out, int out_size, void* d_ws,
                              size_t ws_size, hipStream_t stream) {
  const float* x      = (const float*)d_in[0];
  const float* dw_w   = (const float*)d_in[1];
  const float* dw_g   = (const float*)d_in[2];
  const float* dw_b   = (const float*)d_in[3];
  const float* dw_m   = (const float*)d_in[4];
  const float* dw_v   = (const float*)d_in[5];
  const float* q_w    = (const float*)d_in[6];
  const float* q_g    = (const float*)d_in[7];
  const float* q_b    = (const float*)d_in[8];
  const float* q_m    = (const float*)d_in[9];
  const float* q_v    = (const float*)d_in[10];
  const float* k_w    = (const float*)d_in[11];
  const float* k_g    = (const float*)d_in[12];
  const float* k_b    = (const float*)d_in[13];
  const float* k_m    = (const float*)d_in[14];
  const float* k_v    = (const float*)d_in[15];
  const float* v_w    = (const float*)d_in[16];
  const float* v_g    = (const float*)d_in[17];
  const float* v_b    = (const float*)d_in[18];
  const float* v_m    = (const float*)d_in[19];
  const float* v_v    = (const float*)d_in[20];
  const float* proj_w = (const float*)d_in[21];
  const float* proj_g = (const float*)d_in[22];
  const float* proj_b = (const float*)d_in[23];
  const float* proj_m = (const float*)d_in[24];
  const float* proj_v = (const float*)d_in[25];
  const float* attn_bias = (const float*)d_in[26];

  // Workspace layout (f32): xi | q | k | v | ohead  -> 42.6 MB total.
  float* ws = (float*)d_ws;
  float* xi_buf = ws;                                  // B*64*N
  float* q_buf  = xi_buf + (size_t)kB * kHD * kN;      // B*16*N
  float* k_buf  = q_buf + (size_t)kB * kKD * kN;       // B*16*N
  float* v_buf  = k_buf + (size_t)kB * kKD * kN;       // B*64*N
  float* ohead  = v_buf + (size_t)kB * kD * kN;        // B*256*N

  for (int head = 0; head < kNH; ++head) {
    dwconv_bn_kernel<<<kB * kHD, 256, 0, stream>>>(
        x, dw_w, dw_g, dw_b, dw_m, dw_v, ohead, xi_buf, head,
        head > 0 ? 1 : 0);

    const int qkv_total = kB * 96 * kN;  // 2,457,600
    qkv_kernel<<<(qkv_total + 255) / 256, 256, 0, stream>>>(
        xi_buf, q_w, q_g, q_b, q_m, q_v, k_w, k_g, k_b, k_m, k_v, v_w, v_g,
        v_b, v_m, v_v, q_buf, k_buf, v_buf, head);

    attn_kernel<<<kB * kN, 256, 0, stream>>>(q_buf, k_buf, v_buf, attn_bias,
                                             ohead, head);
  }

  const int proj_total = kB * kDIM * kN;  // 6,553,600
  proj_kernel<<<(proj_total + 255) / 256, 256, 0, stream>>>(
      ohead, proj_w, proj_g, proj_b, proj_m, proj_v, (float*)d_out);
}

// Round 3
// 1040.205 us; speedup vs baseline: 9.6551x; 9.6551x over previous
//
#include <hip/hip_runtime.h>
#include <cstddef>

namespace {
constexpr int kNH  = 4;
constexpr int kKD  = 16;
constexpr int kHD  = 64;
constexpr int kD   = 64;
constexpr int kRES = 40;
constexpr int kN   = 1600;   // 40*40
constexpr int kB   = 16;
constexpr int kDIM = 256;
constexpr float kEPS   = 1e-5f;
constexpr float kSCALE = 0.25f;          // KD^-0.5
constexpr float kLOG2E = 1.4426950408889634f;
constexpr float kC1    = kSCALE * kLOG2E;
}  // namespace

typedef __attribute__((ext_vector_type(8)))  short short8;
typedef __attribute__((ext_vector_type(4)))  float f32x4;
typedef __attribute__((ext_vector_type(16))) float f32x16;

// f32 -> bf16 bits, round-nearest-even (values here are finite).
static __device__ __forceinline__ unsigned short f2bf(float x) {
  unsigned u = __builtin_bit_cast(unsigned, x);
  u = (u + 0x7fffu + ((u >> 16) & 1u)) >> 16;
  return (unsigned short)u;
}

// ---------------------------------------------------------------------------
// Kernel 0: bias2 = attn_bias * log2(e)   (6400 elements)
// ---------------------------------------------------------------------------
__global__ __launch_bounds__(256) void bias_prep_kernel(
    const float* __restrict__ attn_bias, float* __restrict__ bias2) {
  const int i = blockIdx.x * 256 + threadIdx.x;
  if (i < kNH * kN) bias2[i] = attn_bias[i] * kLOG2E;
}

// ---------------------------------------------------------------------------
// Kernel 1: depthwise 5x5 conv (SAME) + BN + cascade add (prev head output).
// ---------------------------------------------------------------------------
__global__ __launch_bounds__(256) void dwconv_bn_kernel(
    const float* __restrict__ x,
    const float* __restrict__ dw_w, const float* __restrict__ dw_g,
    const float* __restrict__ dw_b, const float* __restrict__ dw_m,
    const float* __restrict__ dw_v,
    const float* __restrict__ ohead,   // (B,256,N) f32
    float* __restrict__ xi,            // (B,64,N) f32
    int head, int has_prev) {
  const int bc = blockIdx.x;           // b*64 + c
  const int b = bc >> 6;
  const int c = bc & 63;
  const int gc = head * kHD + c;

  const float* xin = x + ((size_t)b * kDIM + gc) * kN;
  const float* wc = dw_w + (size_t)gc * 25;
  float wreg[25];
#pragma unroll
  for (int t = 0; t < 25; ++t) wreg[t] = wc[t];

  const float sc = dw_g[gc] * rsqrtf(dw_v[gc] + kEPS);
  const float sh = dw_b[gc] - dw_m[gc] * sc;

  const float* prev = ohead + ((size_t)b * kDIM + (head - 1) * kD + c) * kN;
  float* xo = xi + ((size_t)b * kHD + c) * kN;

  for (int p = threadIdx.x; p < kN; p += blockDim.x) {
    const int h = p / kRES;
    const int w = p - h * kRES;
    float acc = 0.f;
#pragma unroll
    for (int dh = 0; dh < 5; ++dh) {
      const int hh = h + dh - 2;
      if (hh < 0 || hh >= kRES) continue;
#pragma unroll
      for (int dwi = 0; dwi < 5; ++dwi) {
        const int ww = w + dwi - 2;
        if (ww < 0 || ww >= kRES) continue;
        acc += xin[hh * kRES + ww] * wreg[dh * 5 + dwi];
      }
    }
    float val = acc * sc + sh;
    if (has_prev) val += prev[p];
    xo[p] = val;
  }
}

// ---------------------------------------------------------------------------
// Kernel 2a: Q,K 1x1 conv + BN -> bf16, transposed layout (b, n, 16).
// One thread per (b, n); weights staged in LDS (broadcast reads).
// ---------------------------------------------------------------------------
__global__ __launch_bounds__(256) void qk_t_kernel(
    const float* __restrict__ xi,
    const float* __restrict__ q_w, const float* __restrict__ q_g,
    const float* __restrict__ q_b, const float* __restrict__ q_m,
    const float* __restrict__ q_v,
    const float* __restrict__ k_w, const float* __restrict__ k_g,
    const float* __restrict__ k_b, const float* __restrict__ k_m,
    const float* __restrict__ k_v,
    unsigned short* __restrict__ q_t, unsigned short* __restrict__ k_t,
    int head) {
  __shared__ float sw[2048];  // [0,1024) q weights, [1024,2048) k weights
  for (int i = threadIdx.x; i < 2048; i += 256)
    sw[i] = (i < 1024) ? q_w[(size_t)head * 1024 + i]
                       : k_w[(size_t)head * 1024 + (i - 1024)];
  __syncthreads();

  const int idx = blockIdx.x * 256 + threadIdx.x;  // b*1600 + n
  const int b = idx / kN;
  const float* xin = xi + (size_t)b * kHD * kN + (idx - b * kN);

  float qa[16] = {}, ka[16] = {};
  for (int c = 0; c < kHD; ++c) {
    const float xv = xin[(size_t)c * kN];
#pragma unroll
    for (int ch = 0; ch < 16; ++ch) {
      qa[ch] = fmaf(sw[ch * 64 + c], xv, qa[ch]);
      ka[ch] = fmaf(sw[1024 + ch * 64 + c], xv, ka[ch]);
    }
  }

  short8 qo0, qo1, ko0, ko1;
#pragma unroll
  for (int ch = 0; ch < 16; ++ch) {
    const int r = head * kKD + ch;
    const float qsc = q_g[r] * rsqrtf(q_v[r] + kEPS);
    const float qsh = q_b[r] - q_m[r] * qsc;
    const float ksc = k_g[r] * rsqrtf(k_v[r] + kEPS);
    const float ksh = k_b[r] - k_m[r] * ksc;
    const short qv2 = (short)f2bf(qa[ch] * qsc + qsh);
    const short kv2 = (short)f2bf(ka[ch] * ksc + ksh);
    if (ch < 8) { qo0[ch] = qv2; ko0[ch] = kv2; }
    else        { qo1[ch - 8] = qv2; ko1[ch - 8] = kv2; }
  }
  *(short8*)(q_t + (size_t)idx * 16)     = qo0;
  *(short8*)(q_t + (size_t)idx * 16 + 8) = qo1;
  *(short8*)(k_t + (size_t)idx * 16)     = ko0;
  *(short8*)(k_t + (size_t)idx * 16 + 8) = ko1;
}

// ---------------------------------------------------------------------------
// Kernel 2b: V 1x1 conv + BN -> bf16 (b, d, n) with keys sigma-permuted
// within each 16-block: sigma swaps bits 2 and 3 of (n & 15) (involution).
// ---------------------------------------------------------------------------
__global__ __launch_bounds__(256) void v_perm_kernel(
    const float* __restrict__ xi,
    const float* __restrict__ v_w, const float* __restrict__ v_g,
    const float* __restrict__ v_b, const float* __restrict__ v_m,
    const float* __restrict__ v_v,
    unsigned short* __restrict__ v_p, int head) {
  const int idx = blockIdx.x * 256 + threadIdx.x;  // (b*64+d)*1600 + m
  const int m = idx % kN;
  const int t = idx / kN;    // b*64 + d
  const int d = t & 63;
  const int b = t >> 6;

  const int r = head * kD + d;
  const float* wrow = v_w + (size_t)r * kHD;
  const float* xin = xi + (size_t)b * kHD * kN + m;
  float acc = 0.f;
#pragma unroll 8
  for (int c = 0; c < kHD; ++c) acc = fmaf(wrow[c], xin[(size_t)c * kN], acc);
  const float sc = v_g[r] * rsqrtf(v_v[r] + kEPS);
  const float sh = v_b[r] - v_m[r] * sc;

  const int ml = m & 15;
  const int pos = (m & ~15) | (ml & 3) | ((ml & 4) << 1) | ((ml & 8) >> 1);
  v_p[(size_t)t * kN + pos] = f2bf(acc * sc + sh);
}

// ---------------------------------------------------------------------------
// Kernel 3: MFMA flash attention. One wave = 32 queries, loops 50 key-tiles
// of 32. S^T = mfma(K, Q) (KD=16 exact). C layout: col=lane&31=query,
// row(key)=(r&3)+8*(r>>2)+4*(lane>>5). P^T (bf16) feeds PV directly as the
// B operand; V key order pre-permuted so A reads are contiguous.
// ---------------------------------------------------------------------------
__global__ __launch_bounds__(256) void attn_mfma_kernel(
    const unsigned short* __restrict__ q_t,
    const unsigned short* __restrict__ k_t,
    const unsigned short* __restrict__ v_p,
    const float* __restrict__ bias2,
    float* __restrict__ ohead, int head) {
  const int lane = threadIdx.x & 63;
  const int wid = threadIdx.x >> 6;
  const int qt = blockIdx.x * 4 + wid;
  if (qt >= kN / 32) return;
  const int b = blockIdx.y;
  const int col = lane & 31;
  const int h = lane >> 5;
  const int nq = qt * 32 + col;

  const short8 qf =
      *(const short8*)(q_t + ((size_t)b * kN + nq) * 16 + h * 8);
  const float* bs = bias2 + (size_t)head * kN;
  const unsigned short* vb0 = v_p + ((size_t)(b * kD) + col) * kN;
  const unsigned short* vb1 = v_p + ((size_t)(b * kD) + 32 + col) * kN;

  f32x16 o0 = {}, o1 = {};
  float m = -3.0e38f, l = 0.f;

  for (int kt = 0; kt < kN / 32; ++kt) {
    const int kb = kt * 32;
    const short8 kf =
        *(const short8*)(k_t + ((size_t)b * kN + kb + col) * 16 + h * 8);
    f32x16 c = {};
    c = __builtin_amdgcn_mfma_f32_32x32x16_bf16(kf, qf, c, 0, 0, 0);

    const f32x4 bv0 = *(const f32x4*)(bs + kb + 4 * h);
    const f32x4 bv1 = *(const f32x4*)(bs + kb + 8 + 4 * h);
    const f32x4 bv2 = *(const f32x4*)(bs + kb + 16 + 4 * h);
    const f32x4 bv3 = *(const f32x4*)(bs + kb + 24 + 4 * h);

    float s[16];
#pragma unroll
    for (int r = 0; r < 4; ++r)  s[r]      = fmaf(c[r],      kC1, bv0[r]);
#pragma unroll
    for (int r = 0; r < 4; ++r)  s[4 + r]  = fmaf(c[4 + r],  kC1, bv1[r]);
#pragma unroll
    for (int r = 0; r < 4; ++r)  s[8 + r]  = fmaf(c[8 + r],  kC1, bv2[r]);
#pragma unroll
    for (int r = 0; r < 4; ++r)  s[12 + r] = fmaf(c[12 + r], kC1, bv3[r]);

    float tmax = s[0];
#pragma unroll
    for (int r = 1; r < 16; ++r) tmax = fmaxf(tmax, s[r]);
    tmax = fmaxf(tmax, __shfl_xor(tmax, 32));

    const bool upd = tmax > m + 8.0f;   // defer-max (log2 domain)
    if (__any(upd)) {
      const float alpha = upd ? exp2f(m - tmax) : 1.0f;
      m = upd ? tmax : m;
      l *= alpha;
#pragma unroll
      for (int r = 0; r < 16; ++r) { o0[r] *= alpha; o1[r] *= alpha; }
    }

    short8 p0, p1;
    float lsum = 0.f;
#pragma unroll
    for (int e = 0; e < 8; ++e) {
      const float pe = exp2f(s[e] - m);
      lsum += pe;
      p0[e] = (short)f2bf(pe);
    }
#pragma unroll
    for (int e = 0; e < 8; ++e) {
      const float pe = exp2f(s[8 + e] - m);
      lsum += pe;
      p1[e] = (short)f2bf(pe);
    }
    l += lsum;

    const short8 vf00 = *(const short8*)(vb0 + kb + h * 8);
    const short8 vf01 = *(const short8*)(vb0 + kb + 16 + h * 8);
    const short8 vf10 = *(const short8*)(vb1 + kb + h * 8);
    const short8 vf11 = *(const short8*)(vb1 + kb + 16 + h * 8);
    o0 = __builtin_amdgcn_mfma_f32_32x32x16_bf16(vf00, p0, o0, 0, 0, 0);
    o0 = __builtin_amdgcn_mfma_f32_32x32x16_bf16(vf01, p1, o0, 0, 0, 0);
    o1 = __builtin_amdgcn_mfma_f32_32x32x16_bf16(vf10, p0, o1, 0, 0, 0);
    o1 = __builtin_amdgcn_mfma_f32_32x32x16_bf16(vf11, p1, o1, 0, 0, 0);
  }

  l += __shfl_xor(l, 32);
  const float inv = 1.0f / l;

  float* ob = ohead + ((size_t)b * kDIM + head * kD) * kN + nq;
#pragma unroll
  for (int r = 0; r < 16; ++r) {
    const int dim = (r & 3) + 8 * (r >> 2) + 4 * h;
    ob[(size_t)dim * kN] = o0[r] * inv;
    ob[(size_t)(32 + dim) * kN] = o1[r] * inv;
  }
}

// ---------------------------------------------------------------------------
// Kernel 4: projection 1x1 conv (256->256) + BN + ReLU (f32).
// ---------------------------------------------------------------------------
__global__ __launch_bounds__(256) void proj_kernel(
    const float* __restrict__ ohead, const float* __restrict__ pw,
    const float* __restrict__ pg, const float* __restrict__ pb,
    const float* __restrict__ pm, const float* __restrict__ pv,
    float* __restrict__ out) {
  const int idx = blockIdx.x * blockDim.x + threadIdx.x;
  const int n = idx % kN;
  const int t = idx / kN;
  const int o = t % kDIM;
  const int b = t / kDIM;
  if (b >= kB) return;
  const float* wrow = pw + (size_t)o * kDIM;
  const float* xin = ohead + (size_t)b * kDIM * kN + n;
  float acc = 0.f;
#pragma unroll 8
  for (int c = 0; c < kDIM; ++c) acc += wrow[c] * xin[(size_t)c * kN];
  const float sc = pg[o] * rsqrtf(pv[o] + kEPS);
  const float val = (acc - pm[o]) * sc + pb[o];
  out[idx] = fmaxf(val, 0.f);
}

// ---------------------------------------------------------------------------
extern "C" void kernel_launch(void* const* d_in, const int* in_sizes, int n_in,
                              void* d_out, int out_size, void* d_ws,
                              size_t ws_size, hipStream_t stream) {
  const float* x      = (const float*)d_in[0];
  const float* dw_w   = (const float*)d_in[1];
  const float* dw_g   = (const float*)d_in[2];
  const float* dw_b   = (const float*)d_in[3];
  const float* dw_m   = (const float*)d_in[4];
  const float* dw_v   = (const float*)d_in[5];
  const float* q_w    = (const float*)d_in[6];
  const float* q_g    = (const float*)d_in[7];
  const float* q_b    = (const float*)d_in[8];
  const float* q_m    = (const float*)d_in[9];
  const float* q_v    = (const float*)d_in[10];
  const float* k_w    = (const float*)d_in[11];
  const float* k_g    = (const float*)d_in[12];
  const float* k_b    = (const float*)d_in[13];
  const float* k_m    = (const float*)d_in[14];
  const float* k_v    = (const float*)d_in[15];
  const float* v_w    = (const float*)d_in[16];
  const float* v_g    = (const float*)d_in[17];
  const float* v_b    = (const float*)d_in[18];
  const float* v_m    = (const float*)d_in[19];
  const float* v_v    = (const float*)d_in[20];
  const float* proj_w = (const float*)d_in[21];
  const float* proj_g = (const float*)d_in[22];
  const float* proj_b = (const float*)d_in[23];
  const float* proj_m = (const float*)d_in[24];
  const float* proj_v = (const float*)d_in[25];
  const float* attn_bias = (const float*)d_in[26];

  // Workspace layout (float units):
  //   xi (B*64*N) | ohead (B*256*N) | bias2 (4*N) | q_t | k_t | v_perm (bf16)
  float* ws = (float*)d_ws;
  float* xi_buf = ws;                                    // 1,638,400 f
  float* ohead  = xi_buf + (size_t)kB * kHD * kN;        // 6,553,600 f
  float* bias2  = ohead + (size_t)kB * kDIM * kN;        // 6,400 f
  unsigned short* q_t = (unsigned short*)(bias2 + kNH * kN);      // 409,600 bf16
  unsigned short* k_t = q_t + (size_t)kB * kN * kKD;              // 409,600 bf16
  unsigned short* v_p = k_t + (size_t)kB * kN * kKD;              // 1,638,400 bf16

  bias_prep_kernel<<<(kNH * kN + 255) / 256, 256, 0, stream>>>(attn_bias,
                                                              bias2);

  for (int head = 0; head < kNH; ++head) {
    dwconv_bn_kernel<<<kB * kHD, 256, 0, stream>>>(
        x, dw_w, dw_g, dw_b, dw_m, dw_v, ohead, xi_buf, head,
        head > 0 ? 1 : 0);

    qk_t_kernel<<<(kB * kN) / 256, 256, 0, stream>>>(
        xi_buf, q_w, q_g, q_b, q_m, q_v, k_w, k_g, k_b, k_m, k_v, q_t, k_t,
        head);

    v_perm_kernel<<<(kB * kD * kN) / 256, 256, 0, stream>>>(
        xi_buf, v_w, v_g, v_b, v_m, v_v, v_p, head);

    attn_mfma_kernel<<<dim3(13, kB), 256, 0, stream>>>(q_t, k_t, v_p, bias2,
                                                       ohead, head);
  }

  const int proj_total = kB * kDIM * kN;
  proj_kernel<<<(proj_total + 255) / 256, 256, 0, stream>>>(
      ohead, proj_w, proj_g, proj_b, proj_m, proj_v, (float*)d_out);
}

// Round 4
// 726.450 us; speedup vs baseline: 13.8251x; 1.4319x over previous
//
#include <hip/hip_runtime.h>
#include <cstddef>

namespace {
constexpr int kNH  = 4;
constexpr int kKD  = 16;
constexpr int kHD  = 64;
constexpr int kD   = 64;
constexpr int kRES = 40;
constexpr int kN   = 1600;   // 40*40
constexpr int kB   = 16;
constexpr int kDIM = 256;
constexpr float kEPS   = 1e-5f;
constexpr float kSCALE = 0.25f;          // KD^-0.5
constexpr float kLOG2E = 1.4426950408889634f;
constexpr float kC1    = kSCALE * kLOG2E;
}  // namespace

typedef __attribute__((ext_vector_type(8)))  short short8;
typedef __attribute__((ext_vector_type(4)))  float f32x4;
typedef __attribute__((ext_vector_type(16))) float f32x16;

// f32 -> bf16 bits, round-nearest-even (values here are finite).
static __device__ __forceinline__ unsigned short f2bf(float x) {
  unsigned u = __builtin_bit_cast(unsigned, x);
  u = (u + 0x7fffu + ((u >> 16) & 1u)) >> 16;
  return (unsigned short)u;
}

// ---------------------------------------------------------------------------
// Kernel 0: prep — bias2 = attn_bias*log2e; proj_w -> bf16; BN fold psc/psh.
// ---------------------------------------------------------------------------
__global__ __launch_bounds__(256) void prep_kernel(
    const float* __restrict__ attn_bias, const float* __restrict__ proj_w,
    const float* __restrict__ pg, const float* __restrict__ pb,
    const float* __restrict__ pm, const float* __restrict__ pv,
    float* __restrict__ bias2, unsigned short* __restrict__ w_bf,
    float* __restrict__ psc, float* __restrict__ psh) {
  const int i = blockIdx.x * 256 + threadIdx.x;
  if (i < kNH * kN) bias2[i] = attn_bias[i] * kLOG2E;
  if (i < kDIM * kDIM) w_bf[i] = f2bf(proj_w[i]);
  if (i < kDIM) {
    const float sc = pg[i] * rsqrtf(pv[i] + kEPS);
    psc[i] = sc;
    psh[i] = pb[i] - pm[i] * sc;
  }
}

// ---------------------------------------------------------------------------
// Kernel 1: depthwise 5x5 conv (SAME) + BN + cascade add (prev head output).
// ---------------------------------------------------------------------------
__global__ __launch_bounds__(256) void dwconv_bn_kernel(
    const float* __restrict__ x,
    const float* __restrict__ dw_w, const float* __restrict__ dw_g,
    const float* __restrict__ dw_b, const float* __restrict__ dw_m,
    const float* __restrict__ dw_v,
    const float* __restrict__ ohead,   // (B,256,N) f32 (cascade source)
    float* __restrict__ xi,            // (B,64,N) f32
    int head, int has_prev) {
  const int bc = blockIdx.x;           // b*64 + c
  const int b = bc >> 6;
  const int c = bc & 63;
  const int gc = head * kHD + c;

  const float* xin = x + ((size_t)b * kDIM + gc) * kN;
  const float* wc = dw_w + (size_t)gc * 25;
  float wreg[25];
#pragma unroll
  for (int t = 0; t < 25; ++t) wreg[t] = wc[t];

  const float sc = dw_g[gc] * rsqrtf(dw_v[gc] + kEPS);
  const float sh = dw_b[gc] - dw_m[gc] * sc;

  const float* prev = ohead + ((size_t)b * kDIM + (head - 1) * kD + c) * kN;
  float* xo = xi + ((size_t)b * kHD + c) * kN;

  for (int p = threadIdx.x; p < kN; p += blockDim.x) {
    const int h = p / kRES;
    const int w = p - h * kRES;
    float acc = 0.f;
#pragma unroll
    for (int dh = 0; dh < 5; ++dh) {
      const int hh = h + dh - 2;
      if (hh < 0 || hh >= kRES) continue;
#pragma unroll
      for (int dwi = 0; dwi < 5; ++dwi) {
        const int ww = w + dwi - 2;
        if (ww < 0 || ww >= kRES) continue;
        acc += xin[hh * kRES + ww] * wreg[dh * 5 + dwi];
      }
    }
    float val = acc * sc + sh;
    if (has_prev) val += prev[p];
    xo[p] = val;
  }
}

// ---------------------------------------------------------------------------
// Kernel 2a: Q,K 1x1 conv + BN -> bf16, transposed layout (b, n, 16).
// ---------------------------------------------------------------------------
__global__ __launch_bounds__(256) void qk_t_kernel(
    const float* __restrict__ xi,
    const float* __restrict__ q_w, const float* __restrict__ q_g,
    const float* __restrict__ q_b, const float* __restrict__ q_m,
    const float* __restrict__ q_v,
    const float* __restrict__ k_w, const float* __restrict__ k_g,
    const float* __restrict__ k_b, const float* __restrict__ k_m,
    const float* __restrict__ k_v,
    unsigned short* __restrict__ q_t, unsigned short* __restrict__ k_t,
    int head) {
  __shared__ float sw[2048];  // [0,1024) q weights, [1024,2048) k weights
  for (int i = threadIdx.x; i < 2048; i += 256)
    sw[i] = (i < 1024) ? q_w[(size_t)head * 1024 + i]
                       : k_w[(size_t)head * 1024 + (i - 1024)];
  __syncthreads();

  const int idx = blockIdx.x * 256 + threadIdx.x;  // b*1600 + n
  const int b = idx / kN;
  const float* xin = xi + (size_t)b * kHD * kN + (idx - b * kN);

  float qa[16] = {}, ka[16] = {};
  for (int c = 0; c < kHD; ++c) {
    const float xv = xin[(size_t)c * kN];
#pragma unroll
    for (int ch = 0; ch < 16; ++ch) {
      qa[ch] = fmaf(sw[ch * 64 + c], xv, qa[ch]);
      ka[ch] = fmaf(sw[1024 + ch * 64 + c], xv, ka[ch]);
    }
  }

  short8 qo0, qo1, ko0, ko1;
#pragma unroll
  for (int ch = 0; ch < 16; ++ch) {
    const int r = head * kKD + ch;
    const float qsc = q_g[r] * rsqrtf(q_v[r] + kEPS);
    const float qsh = q_b[r] - q_m[r] * qsc;
    const float ksc = k_g[r] * rsqrtf(k_v[r] + kEPS);
    const float ksh = k_b[r] - k_m[r] * ksc;
    const short qv2 = (short)f2bf(qa[ch] * qsc + qsh);
    const short kv2 = (short)f2bf(ka[ch] * ksc + ksh);
    if (ch < 8) { qo0[ch] = qv2; ko0[ch] = kv2; }
    else        { qo1[ch - 8] = qv2; ko1[ch - 8] = kv2; }
  }
  *(short8*)(q_t + (size_t)idx * 16)     = qo0;
  *(short8*)(q_t + (size_t)idx * 16 + 8) = qo1;
  *(short8*)(k_t + (size_t)idx * 16)     = ko0;
  *(short8*)(k_t + (size_t)idx * 16 + 8) = ko1;
}

// ---------------------------------------------------------------------------
// Kernel 2b: V 1x1 conv + BN -> bf16 (b, d, n), keys sigma-permuted within
// each 16-block (swap bits 2<->3 of n&15; involution).
// ---------------------------------------------------------------------------
__global__ __launch_bounds__(256) void v_perm_kernel(
    const float* __restrict__ xi,
    const float* __restrict__ v_w, const float* __restrict__ v_g,
    const float* __restrict__ v_b, const float* __restrict__ v_m,
    const float* __restrict__ v_v,
    unsigned short* __restrict__ v_p, int head) {
  const int idx = blockIdx.x * 256 + threadIdx.x;  // (b*64+d)*1600 + m
  const int m = idx % kN;
  const int t = idx / kN;    // b*64 + d
  const int d = t & 63;
  const int b = t >> 6;

  const int r = head * kD + d;
  const float* wrow = v_w + (size_t)r * kHD;
  const float* xin = xi + (size_t)b * kHD * kN + m;
  float acc = 0.f;
#pragma unroll 8
  for (int c = 0; c < kHD; ++c) acc = fmaf(wrow[c], xin[(size_t)c * kN], acc);
  const float sc = v_g[r] * rsqrtf(v_v[r] + kEPS);
  const float sh = v_b[r] - v_m[r] * sc;

  const int ml = m & 15;
  const int pos = (m & ~15) | (ml & 3) | ((ml & 4) << 1) | ((ml & 8) >> 1);
  v_p[(size_t)t * kN + pos] = f2bf(acc * sc + sh);
}

// ---------------------------------------------------------------------------
// Kernel 3: MFMA flash attention (verified fragment mappings).
// Epilogue writes f32 ohead (cascade, heads 0-2) + bf16 o_bf (b,n,c) for
// the proj GEMM's B operand.
// ---------------------------------------------------------------------------
__global__ __launch_bounds__(256) void attn_mfma_kernel(
    const unsigned short* __restrict__ q_t,
    const unsigned short* __restrict__ k_t,
    const unsigned short* __restrict__ v_p,
    const float* __restrict__ bias2,
    float* __restrict__ ohead, unsigned short* __restrict__ o_bf,
    int head, int wr_f32) {
  const int lane = threadIdx.x & 63;
  const int wid = threadIdx.x >> 6;
  const int qt = blockIdx.x * 4 + wid;
  if (qt >= kN / 32) return;
  const int b = blockIdx.y;
  const int col = lane & 31;
  const int h = lane >> 5;
  const int nq = qt * 32 + col;

  const short8 qf =
      *(const short8*)(q_t + ((size_t)b * kN + nq) * 16 + h * 8);
  const float* bs = bias2 + (size_t)head * kN;
  const unsigned short* vb0 = v_p + ((size_t)(b * kD) + col) * kN;
  const unsigned short* vb1 = v_p + ((size_t)(b * kD) + 32 + col) * kN;

  f32x16 o0 = {}, o1 = {};
  float m = -3.0e38f, l = 0.f;

  for (int kt = 0; kt < kN / 32; ++kt) {
    const int kb = kt * 32;
    const short8 kf =
        *(const short8*)(k_t + ((size_t)b * kN + kb + col) * 16 + h * 8);
    f32x16 c = {};
    c = __builtin_amdgcn_mfma_f32_32x32x16_bf16(kf, qf, c, 0, 0, 0);

    const f32x4 bv0 = *(const f32x4*)(bs + kb + 4 * h);
    const f32x4 bv1 = *(const f32x4*)(bs + kb + 8 + 4 * h);
    const f32x4 bv2 = *(const f32x4*)(bs + kb + 16 + 4 * h);
    const f32x4 bv3 = *(const f32x4*)(bs + kb + 24 + 4 * h);

    float s[16];
#pragma unroll
    for (int r = 0; r < 4; ++r)  s[r]      = fmaf(c[r],      kC1, bv0[r]);
#pragma unroll
    for (int r = 0; r < 4; ++r)  s[4 + r]  = fmaf(c[4 + r],  kC1, bv1[r]);
#pragma unroll
    for (int r = 0; r < 4; ++r)  s[8 + r]  = fmaf(c[8 + r],  kC1, bv2[r]);
#pragma unroll
    for (int r = 0; r < 4; ++r)  s[12 + r] = fmaf(c[12 + r], kC1, bv3[r]);

    float tmax = s[0];
#pragma unroll
    for (int r = 1; r < 16; ++r) tmax = fmaxf(tmax, s[r]);
    tmax = fmaxf(tmax, __shfl_xor(tmax, 32));

    const bool upd = tmax > m + 8.0f;   // defer-max (log2 domain)
    if (__any(upd)) {
      const float alpha = upd ? exp2f(m - tmax) : 1.0f;
      m = upd ? tmax : m;
      l *= alpha;
#pragma unroll
      for (int r = 0; r < 16; ++r) { o0[r] *= alpha; o1[r] *= alpha; }
    }

    short8 p0, p1;
    float lsum = 0.f;
#pragma unroll
    for (int e = 0; e < 8; ++e) {
      const float pe = exp2f(s[e] - m);
      lsum += pe;
      p0[e] = (short)f2bf(pe);
    }
#pragma unroll
    for (int e = 0; e < 8; ++e) {
      const float pe = exp2f(s[8 + e] - m);
      lsum += pe;
      p1[e] = (short)f2bf(pe);
    }
    l += lsum;

    const short8 vf00 = *(const short8*)(vb0 + kb + h * 8);
    const short8 vf01 = *(const short8*)(vb0 + kb + 16 + h * 8);
    const short8 vf10 = *(const short8*)(vb1 + kb + h * 8);
    const short8 vf11 = *(const short8*)(vb1 + kb + 16 + h * 8);
    o0 = __builtin_amdgcn_mfma_f32_32x32x16_bf16(vf00, p0, o0, 0, 0, 0);
    o0 = __builtin_amdgcn_mfma_f32_32x32x16_bf16(vf01, p1, o0, 0, 0, 0);
    o1 = __builtin_amdgcn_mfma_f32_32x32x16_bf16(vf10, p0, o1, 0, 0, 0);
    o1 = __builtin_amdgcn_mfma_f32_32x32x16_bf16(vf11, p1, o1, 0, 0, 0);
  }

  l += __shfl_xor(l, 32);
  const float inv = 1.0f / l;

  float* ob = ohead + ((size_t)b * kDIM + head * kD) * kN + nq;
  unsigned short* obf =
      o_bf + ((size_t)b * kN + nq) * kDIM + head * kD;
#pragma unroll
  for (int r = 0; r < 16; ++r) {
    const int dim = (r & 3) + 8 * (r >> 2) + 4 * h;
    const float v0 = o0[r] * inv;
    const float v1 = o1[r] * inv;
    if (wr_f32) {
      ob[(size_t)dim * kN] = v0;
      ob[(size_t)(32 + dim) * kN] = v1;
    }
    obf[dim] = f2bf(v0);
    obf[dim + 32] = f2bf(v1);
  }
}

// ---------------------------------------------------------------------------
// Kernel 4: projection GEMM via MFMA. C[o, (b,n)] = W[o,c] * o_bf[(b,n), c].
// One wave = 32 o x 32 n tile, 16 k-steps. BN+ReLU fused in epilogue.
// ---------------------------------------------------------------------------
__global__ __launch_bounds__(256) void proj_mfma_kernel(
    const unsigned short* __restrict__ o_bf,   // (B, N, 256) bf16
    const unsigned short* __restrict__ w_bf,   // (256, 256) bf16
    const float* __restrict__ psc, const float* __restrict__ psh,
    float* __restrict__ out) {
  const int lane = threadIdx.x & 63;
  const int wid = threadIdx.x >> 6;
  const int t = blockIdx.x * 4 + wid;          // [0, 6400)
  const int b = t / 400;
  const int rem = t - b * 400;
  const int ot = rem / 50;
  const int nt = rem - ot * 50;
  const int col = lane & 31;
  const int h = lane >> 5;

  const unsigned short* arow = w_bf + ((size_t)(ot * 32 + col)) * kDIM + h * 8;
  const unsigned short* brow =
      o_bf + ((size_t)(b * kN + nt * 32 + col)) * kDIM + h * 8;

  f32x16 acc = {};
#pragma unroll
  for (int k = 0; k < 16; ++k) {
    const short8 af = *(const short8*)(arow + k * 16);
    const short8 bfr = *(const short8*)(brow + k * 16);
    acc = __builtin_amdgcn_mfma_f32_32x32x16_bf16(af, bfr, acc, 0, 0, 0);
  }

  float* ob = out + (size_t)b * kDIM * kN + nt * 32 + col;
#pragma unroll
  for (int r = 0; r < 16; ++r) {
    const int o = ot * 32 + (r & 3) + 8 * (r >> 2) + 4 * h;
    const float v = acc[r] * psc[o] + psh[o];
    ob[(size_t)o * kN] = fmaxf(v, 0.f);
  }
}

// ---------------------------------------------------------------------------
extern "C" void kernel_launch(void* const* d_in, const int* in_sizes, int n_in,
                              void* d_out, int out_size, void* d_ws,
                              size_t ws_size, hipStream_t stream) {
  const float* x      = (const float*)d_in[0];
  const float* dw_w   = (const float*)d_in[1];
  const float* dw_g   = (const float*)d_in[2];
  const float* dw_b   = (const float*)d_in[3];
  const float* dw_m   = (const float*)d_in[4];
  const float* dw_v   = (const float*)d_in[5];
  const float* q_w    = (const float*)d_in[6];
  const float* q_g    = (const float*)d_in[7];
  const float* q_b    = (const float*)d_in[8];
  const float* q_m    = (const float*)d_in[9];
  const float* q_v    = (const float*)d_in[10];
  const float* k_w    = (const float*)d_in[11];
  const float* k_g    = (const float*)d_in[12];
  const float* k_b    = (const float*)d_in[13];
  const float* k_m    = (const float*)d_in[14];
  const float* k_v    = (const float*)d_in[15];
  const float* v_w    = (const float*)d_in[16];
  const float* v_g    = (const float*)d_in[17];
  const float* v_b    = (const float*)d_in[18];
  const float* v_m    = (const float*)d_in[19];
  const float* v_v    = (const float*)d_in[20];
  const float* proj_w = (const float*)d_in[21];
  const float* proj_g = (const float*)d_in[22];
  const float* proj_b = (const float*)d_in[23];
  const float* proj_m = (const float*)d_in[24];
  const float* proj_v = (const float*)d_in[25];
  const float* attn_bias = (const float*)d_in[26];

  // Workspace layout (f32 region first, then bf16 region; all 16B aligned):
  float* ws = (float*)d_ws;
  float* xi_buf = ws;                                    // B*64*N f32
  float* ohead  = xi_buf + (size_t)kB * kHD * kN;        // B*256*N f32
  float* bias2  = ohead + (size_t)kB * kDIM * kN;        // 4*N f32
  float* psc    = bias2 + kNH * kN;                      // 256 f32
  float* psh    = psc + kDIM;                            // 256 f32
  unsigned short* q_t = (unsigned short*)(psh + kDIM);   // B*N*16 bf16
  unsigned short* k_t = q_t + (size_t)kB * kN * kKD;     // B*N*16 bf16
  unsigned short* v_p = k_t + (size_t)kB * kN * kKD;     // B*64*N bf16
  unsigned short* o_bf = v_p + (size_t)kB * kD * kN;     // B*N*256 bf16
  unsigned short* w_bf = o_bf + (size_t)kB * kN * kDIM;  // 256*256 bf16

  prep_kernel<<<(kDIM * kDIM + 255) / 256, 256, 0, stream>>>(
      attn_bias, proj_w, proj_g, proj_b, proj_m, proj_v, bias2, w_bf, psc,
      psh);

  for (int head = 0; head < kNH; ++head) {
    dwconv_bn_kernel<<<kB * kHD, 256, 0, stream>>>(
        x, dw_w, dw_g, dw_b, dw_m, dw_v, ohead, xi_buf, head,
        head > 0 ? 1 : 0);

    qk_t_kernel<<<(kB * kN) / 256, 256, 0, stream>>>(
        xi_buf, q_w, q_g, q_b, q_m, q_v, k_w, k_g, k_b, k_m, k_v, q_t, k_t,
        head);

    v_perm_kernel<<<(kB * kD * kN) / 256, 256, 0, stream>>>(
        xi_buf, v_w, v_g, v_b, v_m, v_v, v_p, head);

    attn_mfma_kernel<<<dim3(13, kB), 256, 0, stream>>>(
        q_t, k_t, v_p, bias2, ohead, o_bf, head, head < 3 ? 1 : 0);
  }

  proj_mfma_kernel<<<1600, 256, 0, stream>>>(o_bf, w_bf, psc, psh,
                                             (float*)d_out);
}